// Round 1
// baseline (6034.612 us; speedup 1.0000x reference)
//
#include <hip/hip_runtime.h>

#define BB     2048
#define TT     512
#define INDIM  28
#define HH     64
#define NC     10
#define ROWS   4
#define NTHREADS 128

__device__ __forceinline__ float frcp(float x)  { return __builtin_amdgcn_rcpf(x); }
__device__ __forceinline__ float fsig(float x)  { return frcp(1.f + __expf(-x)); }
// tanh(x) = 1 - 2/(1+e^{2x})
__device__ __forceinline__ float ftanhf(float x){ return fmaf(-2.f, frcp(1.f + __expf(2.f*x)), 1.f); }

extern "C" __global__ __launch_bounds__(NTHREADS, 2)
void gru_fused(const float* __restrict__ x,
               const float* __restrict__ W_ih,
               const float* __restrict__ W_hh,
               const float* __restrict__ b_ih,
               const float* __restrict__ b_hh,
               const float* __restrict__ W_out,
               const float* __restrict__ b_out,
               float* __restrict__ out)
{
    __shared__ __align__(16) float hs[ROWS][HH];   // hidden state, fp32
    __shared__ __align__(16) float xs[ROWS][32];   // x_t staged, padded 28->32 (pad stays 0)
    __shared__ float lg[ROWS][NC];

    const int tid = threadIdx.x;
    const int l   = tid & 63;
    const int w   = tid >> 6;
    const int u   = (l & 31) | (w << 5);  // hidden unit 0..63
    const int m   = l >> 5;               // j-half 0/1 (xor-32 partner within the wave)
    const int r0  = blockIdx.x * ROWS;

    const int mj = m * 32;                // h-slice start
    const int mi = m * 16;                // x-slice start (16/12 split of 28)

    // ---- register-cached weight tiles (fixed across the whole recurrence) ----
    float whh0[32], whh1[32], whh2[32];
    float wih0[16], wih1[16], wih2[16];
    {
        const float* p0 = W_hh + (size_t)(u       ) * HH + mj;
        const float* p1 = W_hh + (size_t)(u +  64 ) * HH + mj;
        const float* p2 = W_hh + (size_t)(u + 128 ) * HH + mj;
        #pragma unroll
        for (int j = 0; j < 32; ++j) { whh0[j] = p0[j]; whh1[j] = p1[j]; whh2[j] = p2[j]; }
        const float* q0 = W_ih + (size_t)(u       ) * INDIM;
        const float* q1 = W_ih + (size_t)(u +  64 ) * INDIM;
        const float* q2 = W_ih + (size_t)(u + 128 ) * INDIM;
        #pragma unroll
        for (int i = 0; i < 16; ++i) {
            const int ii = mi + i;
            const bool ok = (ii < INDIM);
            wih0[i] = ok ? q0[ii] : 0.f;
            wih1[i] = ok ? q1[ii] : 0.f;
            wih2[i] = ok ? q2[ii] : 0.f;
        }
    }
    const float bs0  = b_ih[u]       + b_hh[u];        // r-gate bias (merged)
    const float bs1  = b_ih[u + 64]  + b_hh[u + 64];   // z-gate bias (merged)
    const float bihn = b_ih[u + 128];                  // n-gate x bias
    const float bhhn = b_hh[u + 128];                  // n-gate h bias (inside r*(...))

    // ---- init h = 0, zero xs (incl. pad cols 28..31), stage x_t=0 ----
    for (int i = tid; i < ROWS * HH; i += NTHREADS) ((float*)hs)[i] = 0.f;
    for (int i = tid; i < ROWS * 32; i += NTHREADS) ((float*)xs)[i] = 0.f;
    const int srow = tid / INDIM;
    const int scol = tid % INDIM;
    const float* xbase = x + (size_t)(r0 + srow) * TT * INDIM + scol;
    if (tid < ROWS * INDIM) xs[srow][scol] = xbase[0];
    __syncthreads();

    // ---- recurrence ----
    for (int t = 0; t < TT; ++t) {
        // prefetch next timestep's x while computing (consumed after the barrier)
        float xnext = 0.f;
        if (t + 1 < TT && tid < ROWS * INDIM) xnext = xbase[(size_t)(t + 1) * INDIM];

        float a0[ROWS], a1[ROWS], ah[ROWS], ax[ROWS];
        #pragma unroll
        for (int rr = 0; rr < ROWS; ++rr) {
            float s0 = 0.f, s1 = 0.f, sh = 0.f, sx = 0.f;
            const float4* hp = (const float4*)(&hs[rr][mj]);
            #pragma unroll
            for (int c = 0; c < 8; ++c) {
                const float4 hv = hp[c];
                s0 = fmaf(whh0[4*c+0], hv.x, s0); s0 = fmaf(whh0[4*c+1], hv.y, s0);
                s0 = fmaf(whh0[4*c+2], hv.z, s0); s0 = fmaf(whh0[4*c+3], hv.w, s0);
                s1 = fmaf(whh1[4*c+0], hv.x, s1); s1 = fmaf(whh1[4*c+1], hv.y, s1);
                s1 = fmaf(whh1[4*c+2], hv.z, s1); s1 = fmaf(whh1[4*c+3], hv.w, s1);
                sh = fmaf(whh2[4*c+0], hv.x, sh); sh = fmaf(whh2[4*c+1], hv.y, sh);
                sh = fmaf(whh2[4*c+2], hv.z, sh); sh = fmaf(whh2[4*c+3], hv.w, sh);
            }
            const float4* xp = (const float4*)(&xs[rr][mi]);
            #pragma unroll
            for (int c = 0; c < 4; ++c) {
                const float4 xv = xp[c];
                s0 = fmaf(wih0[4*c+0], xv.x, s0); s0 = fmaf(wih0[4*c+1], xv.y, s0);
                s0 = fmaf(wih0[4*c+2], xv.z, s0); s0 = fmaf(wih0[4*c+3], xv.w, s0);
                s1 = fmaf(wih1[4*c+0], xv.x, s1); s1 = fmaf(wih1[4*c+1], xv.y, s1);
                s1 = fmaf(wih1[4*c+2], xv.z, s1); s1 = fmaf(wih1[4*c+3], xv.w, s1);
                sx = fmaf(wih2[4*c+0], xv.x, sx); sx = fmaf(wih2[4*c+1], xv.y, sx);
                sx = fmaf(wih2[4*c+2], xv.z, sx); sx = fmaf(wih2[4*c+3], xv.w, sx);
            }
            a0[rr] = s0; a1[rr] = s1; ah[rr] = sh; ax[rr] = sx;
        }

        // combine the two j-halves (lanes l and l^32 hold the same (u, rows))
        #pragma unroll
        for (int rr = 0; rr < ROWS; ++rr) {
            a0[rr] += __shfl_xor(a0[rr], 32);
            a1[rr] += __shfl_xor(a1[rr], 32);
            ah[rr] += __shfl_xor(ah[rr], 32);
            ax[rr] += __shfl_xor(ax[rr], 32);
        }

        // gate math: half m handles rows 2m, 2m+1 (compile-time reg indices + cndmask)
        float hn[2];
        #pragma unroll
        for (int k = 0; k < 2; ++k) {
            const float v0 = m ? a0[2 + k] : a0[k];
            const float v1 = m ? a1[2 + k] : a1[k];
            const float vh = m ? ah[2 + k] : ah[k];
            const float vx = m ? ax[2 + k] : ax[k];
            const int rr = 2 * m + k;
            const float rg   = fsig(v0 + bs0);
            const float zg   = fsig(v1 + bs1);
            const float ng   = ftanhf(vx + bihn + rg * (vh + bhhn));
            const float hold = hs[rr][u];
            hn[k] = fmaf(zg, hold - ng, ng);   // (1-z)*n + z*h
        }
        __syncthreads();   // all reads of hs/xs done
        hs[2 * m    ][u] = hn[0];
        hs[2 * m + 1][u] = hn[1];
        if (t + 1 < TT && tid < ROWS * INDIM) xs[srow][scol] = xnext;
        __syncthreads();   // new h / x_t visible
    }

    // ---- epilogue: logits + softmax for this block's 4 rows ----
    if (tid < ROWS * NC) {
        const int rr = tid / NC, c = tid % NC;
        float s = b_out[c];
        const float* wo = W_out + (size_t)c * HH;
        #pragma unroll
        for (int j = 0; j < HH; ++j) s = fmaf(wo[j], hs[rr][j], s);
        lg[rr][c] = s;
    }
    __syncthreads();
    if (tid < ROWS) {
        float mx = -1e30f;
        #pragma unroll
        for (int c = 0; c < NC; ++c) mx = fmaxf(mx, lg[tid][c]);
        float e[NC]; float ssum = 0.f;
        #pragma unroll
        for (int c = 0; c < NC; ++c) { e[c] = __expf(lg[tid][c] - mx); ssum += e[c]; }
        const float inv = 1.f / ssum;
        float* op = out + (size_t)(r0 + tid) * NC;
        #pragma unroll
        for (int c = 0; c < NC; ++c) op[c] = e[c] * inv;
    }
}

extern "C" void kernel_launch(void* const* d_in, const int* in_sizes, int n_in,
                              void* d_out, int out_size, void* d_ws, size_t ws_size,
                              hipStream_t stream) {
    const float* x     = (const float*)d_in[0];
    const float* W_ih  = (const float*)d_in[1];
    const float* W_hh  = (const float*)d_in[2];
    const float* b_ih  = (const float*)d_in[3];
    const float* b_hh  = (const float*)d_in[4];
    const float* W_out = (const float*)d_in[5];
    const float* b_out = (const float*)d_in[6];
    (void)in_sizes; (void)n_in; (void)d_ws; (void)ws_size; (void)out_size;

    gru_fused<<<BB / ROWS, NTHREADS, 0, stream>>>(x, W_ih, W_hh, b_ih, b_hh,
                                                  W_out, b_out, (float*)d_out);
}

// Round 2
// 894.176 us; speedup vs baseline: 6.7488x; 6.7488x over previous
//
#include <hip/hip_runtime.h>

#define BB     2048
#define TT     512
#define INDIM  28
#define HH     64
#define NC     10
#define ROWS   4
#define NTHREADS 256

__device__ __forceinline__ float frcp(float v)  { return __builtin_amdgcn_rcpf(v); }
__device__ __forceinline__ float fsig(float v)  { return frcp(1.f + __expf(-v)); }
// tanh(x) = 1 - 2/(1+e^{2x})
__device__ __forceinline__ float ftanh_(float v){ return fmaf(-2.f, frcp(1.f + __expf(2.f*v)), 1.f); }

// Thread = (hidden unit u in [0,64), j-quarter m in [0,4)).
// Weights per thread: 3 gates x 16 W_hh cols + 3 gates x 8 W_ih cols = 72 floats
// (fits registers with slack; round-1's 144 floats spilled to scratch -> 20 GB HBM).
extern "C" __global__ __launch_bounds__(NTHREADS, 1)
void gru_fused(const float* __restrict__ x,
               const float* __restrict__ W_ih,
               const float* __restrict__ W_hh,
               const float* __restrict__ b_ih,
               const float* __restrict__ b_hh,
               const float* __restrict__ W_out,
               const float* __restrict__ b_out,
               float* __restrict__ out)
{
    __shared__ __align__(16) float hs[ROWS][HH];   // hidden state (fp32)
    __shared__ __align__(16) float xs[ROWS][32];   // x_t staged, 28 padded to 32
    __shared__ float lg[ROWS][NC];

    const int tid = threadIdx.x;
    const int l   = tid & 63;
    const int w   = tid >> 6;
    const int u   = (w << 4) | (l & 15);   // hidden unit 0..63
    const int m   = l >> 4;                // j-quarter 0..3 (lane bits 4,5 -> xor16/xor32 partners)
    const int r0  = blockIdx.x * ROWS;

    // ---- register-cached weight tiles ----
    float whh0[16], whh1[16], whh2[16];
    float wih0[8],  wih1[8],  wih2[8];
    {
        const float* p0 = W_hh + (size_t)(u      ) * HH + m * 16;
        const float* p1 = W_hh + (size_t)(u +  64) * HH + m * 16;
        const float* p2 = W_hh + (size_t)(u + 128) * HH + m * 16;
        #pragma unroll
        for (int j = 0; j < 16; ++j) { whh0[j] = p0[j]; whh1[j] = p1[j]; whh2[j] = p2[j]; }
        const float* q0 = W_ih + (size_t)(u      ) * INDIM;
        const float* q1 = W_ih + (size_t)(u +  64) * INDIM;
        const float* q2 = W_ih + (size_t)(u + 128) * INDIM;
        #pragma unroll
        for (int i = 0; i < 8; ++i) {
            const int ii = m * 8 + i;
            const bool ok = (ii < INDIM);
            wih0[i] = ok ? q0[ii] : 0.f;
            wih1[i] = ok ? q1[ii] : 0.f;
            wih2[i] = ok ? q2[ii] : 0.f;
        }
    }
    const float bs0  = b_ih[u]       + b_hh[u];        // r-gate bias (merged)
    const float bs1  = b_ih[u + 64]  + b_hh[u + 64];   // z-gate bias (merged)
    const float bihn = b_ih[u + 128];                  // n-gate x bias
    const float bhhn = b_hh[u + 128];                  // n-gate h bias (inside r*(...))

    // ---- init h = 0, zero xs (incl. pad cols), stage x_0 ----
    for (int i = tid; i < ROWS * HH; i += NTHREADS) ((float*)hs)[i] = 0.f;
    for (int i = tid; i < ROWS * 32; i += NTHREADS) ((float*)xs)[i] = 0.f;
    const int srow = tid / INDIM;
    const int scol = tid % INDIM;
    const float* xbase = x + (size_t)(r0 + srow) * TT * INDIM + scol;
    if (tid < ROWS * INDIM) xs[srow][scol] = xbase[0];
    __syncthreads();

    // ---- recurrence ----
    for (int t = 0; t < TT; ++t) {
        float xnext = 0.f;
        if (t + 1 < TT && tid < ROWS * INDIM) xnext = xbase[(size_t)(t + 1) * INDIM];

        float a0[ROWS], a1[ROWS], ah[ROWS], ax[ROWS];
        #pragma unroll
        for (int rr = 0; rr < ROWS; ++rr) {
            float s0 = 0.f, s1 = 0.f, sh = 0.f, sx = 0.f;
            const float4* hp = (const float4*)(&hs[rr][m * 16]);
            #pragma unroll
            for (int c = 0; c < 4; ++c) {
                const float4 hv = hp[c];
                s0 = fmaf(whh0[4*c+0], hv.x, s0); s0 = fmaf(whh0[4*c+1], hv.y, s0);
                s0 = fmaf(whh0[4*c+2], hv.z, s0); s0 = fmaf(whh0[4*c+3], hv.w, s0);
                s1 = fmaf(whh1[4*c+0], hv.x, s1); s1 = fmaf(whh1[4*c+1], hv.y, s1);
                s1 = fmaf(whh1[4*c+2], hv.z, s1); s1 = fmaf(whh1[4*c+3], hv.w, s1);
                sh = fmaf(whh2[4*c+0], hv.x, sh); sh = fmaf(whh2[4*c+1], hv.y, sh);
                sh = fmaf(whh2[4*c+2], hv.z, sh); sh = fmaf(whh2[4*c+3], hv.w, sh);
            }
            const float4* xp = (const float4*)(&xs[rr][m * 8]);
            #pragma unroll
            for (int c = 0; c < 2; ++c) {
                const float4 xv = xp[c];
                s0 = fmaf(wih0[4*c+0], xv.x, s0); s0 = fmaf(wih0[4*c+1], xv.y, s0);
                s0 = fmaf(wih0[4*c+2], xv.z, s0); s0 = fmaf(wih0[4*c+3], xv.w, s0);
                s1 = fmaf(wih1[4*c+0], xv.x, s1); s1 = fmaf(wih1[4*c+1], xv.y, s1);
                s1 = fmaf(wih1[4*c+2], xv.z, s1); s1 = fmaf(wih1[4*c+3], xv.w, s1);
                sx = fmaf(wih2[4*c+0], xv.x, sx); sx = fmaf(wih2[4*c+1], xv.y, sx);
                sx = fmaf(wih2[4*c+2], xv.z, sx); sx = fmaf(wih2[4*c+3], xv.w, sx);
            }
            a0[rr] = s0; a1[rr] = s1; ah[rr] = sh; ax[rr] = sx;
        }

        // combine the 4 j-quarters (lane bits 4,5)
        #pragma unroll
        for (int rr = 0; rr < ROWS; ++rr) {
            a0[rr] += __shfl_xor(a0[rr], 16); a0[rr] += __shfl_xor(a0[rr], 32);
            a1[rr] += __shfl_xor(a1[rr], 16); a1[rr] += __shfl_xor(a1[rr], 32);
            ah[rr] += __shfl_xor(ah[rr], 16); ah[rr] += __shfl_xor(ah[rr], 32);
            ax[rr] += __shfl_xor(ax[rr], 16); ax[rr] += __shfl_xor(ax[rr], 32);
        }

        // quarter m finishes batch-row m (one row per thread)
        float v0 = a0[0], v1 = a1[0], vh = ah[0], vx = ax[0];
        #pragma unroll
        for (int rr = 1; rr < ROWS; ++rr)
            if (m == rr) { v0 = a0[rr]; v1 = a1[rr]; vh = ah[rr]; vx = ax[rr]; }

        const float rg   = fsig(v0 + bs0);
        const float zg   = fsig(v1 + bs1);
        const float ng   = ftanh_(vx + bihn + rg * (vh + bhhn));
        const float hold = hs[m][u];
        const float hnew = fmaf(zg, hold - ng, ng);   // (1-z)*n + z*h

        __syncthreads();   // all reads of hs/xs done
        hs[m][u] = hnew;
        if (t + 1 < TT && tid < ROWS * INDIM) xs[srow][scol] = xnext;
        __syncthreads();   // new h / x_t visible
    }

    // ---- epilogue: logits + softmax ----
    if (tid < ROWS * NC) {
        const int rr = tid / NC, c = tid % NC;
        float s = b_out[c];
        const float* wo = W_out + (size_t)c * HH;
        #pragma unroll
        for (int j = 0; j < HH; ++j) s = fmaf(wo[j], hs[rr][j], s);
        lg[rr][c] = s;
    }
    __syncthreads();
    if (tid < ROWS) {
        float mx = -1e30f;
        #pragma unroll
        for (int c = 0; c < NC; ++c) mx = fmaxf(mx, lg[tid][c]);
        float e[NC]; float ssum = 0.f;
        #pragma unroll
        for (int c = 0; c < NC; ++c) { e[c] = __expf(lg[tid][c] - mx); ssum += e[c]; }
        const float inv = 1.f / ssum;
        float* op = out + (size_t)(r0 + tid) * NC;
        #pragma unroll
        for (int c = 0; c < NC; ++c) op[c] = e[c] * inv;
    }
}

extern "C" void kernel_launch(void* const* d_in, const int* in_sizes, int n_in,
                              void* d_out, int out_size, void* d_ws, size_t ws_size,
                              hipStream_t stream) {
    const float* x     = (const float*)d_in[0];
    const float* W_ih  = (const float*)d_in[1];
    const float* W_hh  = (const float*)d_in[2];
    const float* b_ih  = (const float*)d_in[3];
    const float* b_hh  = (const float*)d_in[4];
    const float* W_out = (const float*)d_in[5];
    const float* b_out = (const float*)d_in[6];
    (void)in_sizes; (void)n_in; (void)d_ws; (void)ws_size; (void)out_size;

    gru_fused<<<BB / ROWS, NTHREADS, 0, stream>>>(x, W_ih, W_hh, b_ih, b_hh,
                                                  W_out, b_out, (float*)d_out);
}

// Round 3
// 428.876 us; speedup vs baseline: 14.0708x; 2.0849x over previous
//
#include <hip/hip_runtime.h>

#define BB     2048
#define TT     512
#define INDIM  28
#define HH     64
#define NC     10
#define ROWS   4
#define NTHREADS 256
#define LDA    104   // padded halfs per A row (208 B: 16B-aligned, bank-stride 20 -> 2-way max)

typedef __attribute__((ext_vector_type(8))) _Float16 f16x8;
typedef __attribute__((ext_vector_type(4))) float     f32x4;

__device__ __forceinline__ float frcp(float v)  { return __builtin_amdgcn_rcpf(v); }
__device__ __forceinline__ float fsig(float v)  { return frcp(1.f + __expf(-v)); }
__device__ __forceinline__ float ftanh_(float v){ return fmaf(-2.f, frcp(1.f + __expf(2.f*v)), 1.f); }

#define MFMA(A_, B_, C_) __builtin_amdgcn_mfma_f32_16x16x32_f16((A_), (B_), (C_), 0, 0, 0)

// Per block: 4 batch rows, padded to a 16-row MFMA A-tile (rows 4..15 stay zero).
// A = [h (k=0..63) | x_t (k=64..91) | 0] as fp16 hi+lo (2-way split => fp32-class accuracy).
// Wave w's 4 C-tiles = gates [r, z, n_h, n_x] for units 16w..16w+15, so each lane
// ends up with r/z/nh/nx of the same (row, unit) in-register: no shuffles, no C round-trip.
// Weights live in 18 register-resident B-fragments; h state lives in lane registers.
extern "C" __global__ __launch_bounds__(NTHREADS, 2)
void gru_mfma(const float* __restrict__ x,
              const float* __restrict__ W_ih,
              const float* __restrict__ W_hh,
              const float* __restrict__ b_ih,
              const float* __restrict__ b_hh,
              const float* __restrict__ W_out,
              const float* __restrict__ b_out,
              float* __restrict__ out)
{
    __shared__ _Float16 Ah[2][16][LDA];
    __shared__ _Float16 Al[2][16][LDA];
    __shared__ float hs_f[ROWS][HH];
    __shared__ float lg[ROWS][NC];

    const int tid = threadIdx.x;
    const int w   = tid >> 6;
    const int l   = tid & 63;
    const int c   = l & 15;          // A row / B col within tile
    const int ks8 = (l >> 4) * 8;    // k-offset within a 32-wide k-step
    const int u   = w * 16 + c;      // hidden unit this lane's B-cols correspond to
    const int r0  = blockIdx.x * ROWS;

    // ---- B fragments (weights), hi/lo fp16, register-resident for the whole kernel ----
    // frag f -> (gate g, kstep s): 0..2:(r,s) 3..5:(z,s) 6..7:(nh,0/1) 8:(nx,2)
    f16x8 Bh[9], Bl[9];
    {
        const int GS[9][2] = {{0,0},{0,1},{0,2},{1,0},{1,1},{1,2},{2,0},{2,1},{3,2}};
        #pragma unroll
        for (int f = 0; f < 9; ++f) {
            const int g = GS[f][0], s = GS[f][1];
            #pragma unroll
            for (int j = 0; j < 8; ++j) {
                const int k = s * 32 + ks8 + j;
                float v = 0.f;
                if (g == 2)      { if (k < 64) v = W_hh[(size_t)(u + 128) * HH + k]; }
                else if (g == 3) { if (k >= 64 && k < 64 + INDIM) v = W_ih[(size_t)(u + 128) * INDIM + (k - 64)]; }
                else {
                    const int ru = u + 64 * g;
                    if (k < 64)              v = W_hh[(size_t)ru * HH + k];
                    else if (k < 64 + INDIM) v = W_ih[(size_t)ru * INDIM + (k - 64)];
                }
                const _Float16 hi = (_Float16)v;
                Bh[f][j] = hi;
                Bl[f][j] = (_Float16)(v - (float)hi);
            }
        }
    }
    const float bs0  = b_ih[u]       + b_hh[u];
    const float bs1  = b_ih[u + 64]  + b_hh[u + 64];
    const float bihn = b_ih[u + 128];
    const float bhhn = b_hh[u + 128];

    // ---- zero both A buffers (pad rows/cols stay zero forever) ----
    for (int i = tid; i < 2 * 16 * LDA; i += NTHREADS) {
        ((_Float16*)Ah)[i] = (_Float16)0.f;
        ((_Float16*)Al)[i] = (_Float16)0.f;
    }
    // stage x_0 into buffer 0
    const int xr = tid / INDIM, xi = tid % INDIM;   // valid for tid < 112
    const float* xbase = x + (size_t)(r0 + xr) * TT * INDIM + xi;
    if (tid < ROWS * INDIM) {
        const float v = xbase[0];
        const _Float16 hi = (_Float16)v;
        Ah[0][xr][64 + xi] = hi;
        Al[0][xr][64 + xi] = (_Float16)(v - (float)hi);
    }
    __syncthreads();

    float h[4] = {0.f, 0.f, 0.f, 0.f};   // rows (l>>4)*4+i; real rows only when l<16
    int p = 0;

    for (int t = 0; t < TT; ++t) {
        // prefetch next x (consumed at the bottom, covered by MFMA+gate phase)
        float xn = 0.f;
        if (t + 1 < TT && tid < ROWS * INDIM) xn = xbase[(size_t)(t + 1) * INDIM];

        // A fragments: lane reads A[row=c][kstep s], 8 consecutive halfs
        f16x8 ah[3], al[3];
        #pragma unroll
        for (int s = 0; s < 3; ++s) {
            ah[s] = *(const f16x8*)&Ah[p][c][s * 32 + ks8];
            al[s] = *(const f16x8*)&Al[p][c][s * 32 + ks8];
        }

        f32x4 acc[4] = {{0,0,0,0},{0,0,0,0},{0,0,0,0},{0,0,0,0}};
        #pragma unroll
        for (int s = 0; s < 3; ++s) {     // r and z gates: k-steps 0..2
            acc[0] = MFMA(ah[s], Bh[0+s], acc[0]);
            acc[0] = MFMA(ah[s], Bl[0+s], acc[0]);
            acc[0] = MFMA(al[s], Bh[0+s], acc[0]);
            acc[1] = MFMA(ah[s], Bh[3+s], acc[1]);
            acc[1] = MFMA(ah[s], Bl[3+s], acc[1]);
            acc[1] = MFMA(al[s], Bh[3+s], acc[1]);
        }
        #pragma unroll
        for (int s = 0; s < 2; ++s) {     // n_h: h part only (k-steps 0,1)
            acc[2] = MFMA(ah[s], Bh[6+s], acc[2]);
            acc[2] = MFMA(ah[s], Bl[6+s], acc[2]);
            acc[2] = MFMA(al[s], Bh[6+s], acc[2]);
        }
        acc[3] = MFMA(ah[2], Bh[8], acc[3]);   // n_x: x part only (k-step 2)
        acc[3] = MFMA(ah[2], Bl[8], acc[3]);
        acc[3] = MFMA(al[2], Bh[8], acc[3]);

        // gate math fully in-lane: acc[g][i] is gate g of (row=(l>>4)*4+i, unit u)
        #pragma unroll
        for (int i = 0; i < 4; ++i) {
            const float rg = fsig(acc[0][i] + bs0);
            const float zg = fsig(acc[1][i] + bs1);
            const float ng = ftanh_(acc[3][i] + bihn + rg * (acc[2][i] + bhhn));
            h[i] = fmaf(zg, h[i] - ng, ng);          // (1-z)*n + z*h
        }
        // write h_{t+1} (real rows 0..3) into the next buffer as fp16 hi/lo
        if (l < 16) {
            #pragma unroll
            for (int i = 0; i < 4; ++i) {
                const _Float16 hi = (_Float16)h[i];
                Ah[p ^ 1][i][u] = hi;
                Al[p ^ 1][i][u] = (_Float16)(h[i] - (float)hi);
            }
        }
        // write x_{t+1} into the next buffer
        if (t + 1 < TT && tid < ROWS * INDIM) {
            const _Float16 hi = (_Float16)xn;
            Ah[p ^ 1][xr][64 + xi] = hi;
            Al[p ^ 1][xr][64 + xi] = (_Float16)(xn - (float)hi);
        }
        __syncthreads();
        p ^= 1;
    }

    // ---- epilogue: logits + softmax ----
    if (l < 16) {
        #pragma unroll
        for (int i = 0; i < 4; ++i) hs_f[i][u] = h[i];
    }
    __syncthreads();
    if (tid < ROWS * NC) {
        const int rr = tid / NC, cc = tid % NC;
        float s = b_out[cc];
        const float* wo = W_out + (size_t)cc * HH;
        #pragma unroll
        for (int j = 0; j < HH; ++j) s = fmaf(wo[j], hs_f[rr][j], s);
        lg[rr][cc] = s;
    }
    __syncthreads();
    if (tid < ROWS) {
        float mx = -1e30f;
        #pragma unroll
        for (int cc = 0; cc < NC; ++cc) mx = fmaxf(mx, lg[tid][cc]);
        float e[NC]; float ssum = 0.f;
        #pragma unroll
        for (int cc = 0; cc < NC; ++cc) { e[cc] = __expf(lg[tid][cc] - mx); ssum += e[cc]; }
        const float inv = 1.f / ssum;
        float* op = out + (size_t)(r0 + tid) * NC;
        #pragma unroll
        for (int cc = 0; cc < NC; ++cc) op[cc] = e[cc] * inv;
    }
}

extern "C" void kernel_launch(void* const* d_in, const int* in_sizes, int n_in,
                              void* d_out, int out_size, void* d_ws, size_t ws_size,
                              hipStream_t stream) {
    const float* x     = (const float*)d_in[0];
    const float* W_ih  = (const float*)d_in[1];
    const float* W_hh  = (const float*)d_in[2];
    const float* b_ih  = (const float*)d_in[3];
    const float* b_hh  = (const float*)d_in[4];
    const float* W_out = (const float*)d_in[5];
    const float* b_out = (const float*)d_in[6];
    (void)in_sizes; (void)n_in; (void)d_ws; (void)ws_size; (void)out_size;

    gru_mfma<<<BB / ROWS, NTHREADS, 0, stream>>>(x, W_ih, W_hh, b_ih, b_hh,
                                                 W_out, b_out, (float*)d_out);
}

// Round 4
// 426.391 us; speedup vs baseline: 14.1528x; 1.0058x over previous
//
#include <hip/hip_runtime.h>

#define BB     2048
#define TT     512
#define INDIM  28
#define HH     64
#define NC     10
#define ROWS   8
#define NTHREADS 256
#define LDA    104   // halfs per A row: 208 B -> every row 16B-aligned, 2-way bank alias max (free)

typedef __attribute__((ext_vector_type(8))) _Float16 f16x8;
typedef __attribute__((ext_vector_type(4))) float     f32x4;

__device__ __forceinline__ float frcp(float v)  { return __builtin_amdgcn_rcpf(v); }
__device__ __forceinline__ float fsig(float v)  { return frcp(1.f + __expf(-v)); }
__device__ __forceinline__ float ftanh_(float v){ return fmaf(-2.f, frcp(1.f + __expf(2.f*v)), 1.f); }

#define MFMA(A_, B_, C_) __builtin_amdgcn_mfma_f32_16x16x32_f16((A_), (B_), (C_), 0, 0, 0)

// A-tile (16 x 96): rows 0-7 = [h_hi | x_hi], rows 8-15 = [h_lo | x_lo] of the SAME
// 8 batch rows. Two MFMAs per tile-kstep (x B_hi, x B_lo) into one acc give
// hi(hi+lo) in C-rows 0-7 and lo(hi+lo) in C-rows 8-15; C-row = 4*(lane>>4)+reg, so
// row r + row r+8 combine is a single __shfl_xor(32). Full (hi+lo)x(hi+lo) product.
// 8 real rows/block -> 256 blocks = 1 block/CU, all CUs busy, zero padding waste.
// Wave w's 4 C-tiles = gates [r, z, n_h, n_x] for units 16w..16w+15: gate math is
// fully in-lane (lanes hi>=2 compute bit-identical duplicates and write the lo part).
extern "C" __global__ __launch_bounds__(NTHREADS, 1)
void gru_mfma(const float* __restrict__ x,
              const float* __restrict__ W_ih,
              const float* __restrict__ W_hh,
              const float* __restrict__ b_ih,
              const float* __restrict__ b_hh,
              const float* __restrict__ W_out,
              const float* __restrict__ b_out,
              float* __restrict__ out)
{
    __shared__ __align__(16) _Float16 A_[2][16][LDA];
    __shared__ float hs_f[ROWS][HH];
    __shared__ float lg[ROWS][NC];

    const int tid = threadIdx.x;
    const int w   = tid >> 6;
    const int l   = tid & 63;
    const int c   = l & 15;          // A row sel / B col / C col
    const int hi  = l >> 4;          // lane quad: k-offset for A/B frags, row-group for C
    const int hi8 = hi * 8;
    const int u   = w * 16 + c;      // hidden unit for this lane's gates
    const int r0  = blockIdx.x * ROWS;

    // ---- B fragments (weights), hi/lo fp16, register-resident ----
    // frag f -> (gate g, kstep s): 0..2:(r,s) 3..5:(z,s) 6..7:(nh,0/1) 8:(nx,2)
    f16x8 Bh[9], Bl[9];
    {
        const int GS[9][2] = {{0,0},{0,1},{0,2},{1,0},{1,1},{1,2},{2,0},{2,1},{3,2}};
        #pragma unroll
        for (int f = 0; f < 9; ++f) {
            const int g = GS[f][0], s = GS[f][1];
            #pragma unroll
            for (int j = 0; j < 8; ++j) {
                const int k = s * 32 + hi8 + j;
                float v = 0.f;
                if (g == 2)      { if (k < 64) v = W_hh[(size_t)(u + 128) * HH + k]; }
                else if (g == 3) { if (k >= 64 && k < 64 + INDIM) v = W_ih[(size_t)(u + 128) * INDIM + (k - 64)]; }
                else {
                    const int ru = u + 64 * g;
                    if (k < 64)              v = W_hh[(size_t)ru * HH + k];
                    else if (k < 64 + INDIM) v = W_ih[(size_t)ru * INDIM + (k - 64)];
                }
                const _Float16 vh = (_Float16)v;
                Bh[f][j] = vh;
                Bl[f][j] = (_Float16)(v - (float)vh);
            }
        }
    }
    const float bs0  = b_ih[u]       + b_hh[u];        // r-gate bias
    const float bs1  = b_ih[u + 64]  + b_hh[u + 64];   // z-gate bias
    const float bihn = b_ih[u + 128];                  // n-gate x bias
    const float bhhn = b_hh[u + 128];                  // n-gate h bias (inside r*(...))

    // ---- zero both A buffers (pad cols 92..103 and pre-h zeros) ----
    for (int i = tid; i < 2 * 16 * LDA; i += NTHREADS) ((_Float16*)A_)[i] = (_Float16)0.f;
    // stage x_0 (hi -> rows 0-7, lo -> rows 8-15)
    const int xr = tid / INDIM, xi = tid % INDIM;      // valid for tid < 224
    const float* xbase = x + (size_t)(r0 + (tid < ROWS * INDIM ? xr : 0)) * TT * INDIM + xi;
    if (tid < ROWS * INDIM) {
        const float v = xbase[0];
        const _Float16 vh = (_Float16)v;
        A_[0][xr    ][64 + xi] = vh;
        A_[0][xr + 8][64 + xi] = (_Float16)(v - (float)vh);
    }
    __syncthreads();

    float h[4] = {0.f, 0.f, 0.f, 0.f};   // batch row 4*(hi&1)+i (dup across hi>>1)
    int p = 0;

    for (int t = 0; t < TT; ++t) {
        float xn = 0.f;
        if (t + 1 < TT && tid < ROWS * INDIM) xn = xbase[(size_t)(t + 1) * INDIM];

        f16x8 af[3];
        #pragma unroll
        for (int s = 0; s < 3; ++s)
            af[s] = *(const f16x8*)&A_[p][c][s * 32 + hi8];

        f32x4 acc[4] = {{0,0,0,0},{0,0,0,0},{0,0,0,0},{0,0,0,0}};
        #pragma unroll
        for (int s = 0; s < 3; ++s) {      // r and z: k-steps 0..2
            acc[0] = MFMA(af[s], Bh[0+s], acc[0]);
            acc[0] = MFMA(af[s], Bl[0+s], acc[0]);
            acc[1] = MFMA(af[s], Bh[3+s], acc[1]);
            acc[1] = MFMA(af[s], Bl[3+s], acc[1]);
        }
        #pragma unroll
        for (int s = 0; s < 2; ++s) {      // n_h: h part only (k-steps 0,1)
            acc[2] = MFMA(af[s], Bh[6+s], acc[2]);
            acc[2] = MFMA(af[s], Bl[6+s], acc[2]);
        }
        acc[3] = MFMA(af[2], Bh[8], acc[3]);   // n_x: x part only (k-step 2)
        acc[3] = MFMA(af[2], Bl[8], acc[3]);

        // combine hi-rows (C rows 0-7) with lo-rows (C rows 8-15): lane xor 32
        #pragma unroll
        for (int g = 0; g < 4; ++g)
            #pragma unroll
            for (int i = 0; i < 4; ++i)
                acc[g][i] += __shfl_xor(acc[g][i], 32);

        // gate math fully in-lane; all 64 lanes valid (hi>=2 are exact duplicates)
        #pragma unroll
        for (int i = 0; i < 4; ++i) {
            const float rg = fsig(acc[0][i] + bs0);
            const float zg = fsig(acc[1][i] + bs1);
            const float ng = ftanh_(acc[3][i] + bihn + rg * (acc[2][i] + bhhn));
            h[i] = fmaf(zg, h[i] - ng, ng);          // (1-z)*n + z*h
        }
        // write h_{t+1}: A-row = 4*hi+i; lanes hi<2 write hi-part, hi>=2 write lo-part
        #pragma unroll
        for (int i = 0; i < 4; ++i) {
            const _Float16 vh = (_Float16)h[i];
            const _Float16 vl = (_Float16)(h[i] - (float)vh);
            A_[p ^ 1][4 * hi + i][u] = (hi >= 2) ? vl : vh;
        }
        if (t + 1 < TT && tid < ROWS * INDIM) {
            const _Float16 vh = (_Float16)xn;
            A_[p ^ 1][xr    ][64 + xi] = vh;
            A_[p ^ 1][xr + 8][64 + xi] = (_Float16)(xn - (float)vh);
        }
        __syncthreads();
        p ^= 1;
    }

    // ---- epilogue: logits + softmax for this block's 8 rows ----
    if (hi < 2) {
        #pragma unroll
        for (int i = 0; i < 4; ++i) hs_f[4 * hi + i][u] = h[i];
    }
    __syncthreads();
    if (tid < ROWS * NC) {
        const int rr = tid / NC, cc = tid % NC;
        float s = b_out[cc];
        const float* wo = W_out + (size_t)cc * HH;
        #pragma unroll
        for (int j = 0; j < HH; ++j) s = fmaf(wo[j], hs_f[rr][j], s);
        lg[rr][cc] = s;
    }
    __syncthreads();
    if (tid < ROWS) {
        float mx = -1e30f;
        #pragma unroll
        for (int cc = 0; cc < NC; ++cc) mx = fmaxf(mx, lg[tid][cc]);
        float e[NC]; float ssum = 0.f;
        #pragma unroll
        for (int cc = 0; cc < NC; ++cc) { e[cc] = __expf(lg[tid][cc] - mx); ssum += e[cc]; }
        const float inv = 1.f / ssum;
        float* op = out + (size_t)(r0 + tid) * NC;
        #pragma unroll
        for (int cc = 0; cc < NC; ++cc) op[cc] = e[cc] * inv;
    }
}

extern "C" void kernel_launch(void* const* d_in, const int* in_sizes, int n_in,
                              void* d_out, int out_size, void* d_ws, size_t ws_size,
                              hipStream_t stream) {
    const float* x     = (const float*)d_in[0];
    const float* W_ih  = (const float*)d_in[1];
    const float* W_hh  = (const float*)d_in[2];
    const float* b_ih  = (const float*)d_in[3];
    const float* b_hh  = (const float*)d_in[4];
    const float* W_out = (const float*)d_in[5];
    const float* b_out = (const float*)d_in[6];
    (void)in_sizes; (void)n_in; (void)d_ws; (void)ws_size; (void)out_size;

    gru_mfma<<<BB / ROWS, NTHREADS, 0, stream>>>(x, W_ih, W_hh, b_ih, b_hh,
                                                 W_out, b_out, (float*)d_out);
}